// Round 7
// baseline (480.370 us; speedup 1.0000x reference)
//
#include <hip/hip_runtime.h>
#include <hip/hip_bf16.h>

// Problem constants
constexpr int Bn = 8, Sn = 2048, En = 512, Hn = 4, Dn = 128;
constexpr int BHn = Bn * Hn;          // 32
constexpr int Mqkv = Bn * Sn;         // 16384

typedef __attribute__((ext_vector_type(8))) short short8;
typedef __attribute__((ext_vector_type(4))) float f32x4;

__device__ __forceinline__ unsigned short f2bf(float f) {
  unsigned int u = __builtin_bit_cast(unsigned int, f);
  u += 0x7FFF + ((u >> 16) & 1);   // round-to-nearest-even
  return (unsigned short)(u >> 16);
}

// publish LDS writes; do NOT drain vmcnt (prefetch loads stay in flight)
__device__ __forceinline__ void bar_pub() {
  asm volatile("s_waitcnt lgkmcnt(0)" ::: "memory");
  __builtin_amdgcn_s_barrier();
  asm volatile("" ::: "memory");
}

// ---------------------------------------------------------------------------
// K1: QKV projection (unchanged).
// ---------------------------------------------------------------------------
__global__ __launch_bounds__(256) void qkv_kernel(
    const float* __restrict__ x, const float* __restrict__ Wq,
    const float* __restrict__ Wk, const float* __restrict__ Wv,
    const float* __restrict__ bq, const float* __restrict__ bk,
    const float* __restrict__ bv, unsigned short* __restrict__ qkv) {
  const int z = blockIdx.z;
  const float* W = (z == 0) ? Wq : (z == 1 ? Wk : Wv);
  const float* bias = (z == 0) ? bq : (z == 1 ? bk : bv);
  unsigned short* out = qkv + (size_t)z * BHn * Sn * Dn;

  __shared__ unsigned short As[128][40];
  __shared__ unsigned short BsT[128][40];

  const int t = threadIdx.x;
  const int l = t & 63, w = t >> 6;
  const int wm = w >> 1, wn = w & 1;
  const int m0 = blockIdx.x * 128, n0 = blockIdx.y * 128;

  f32x4 acc[4][4] = {};

  for (int k0 = 0; k0 < En; k0 += 32) {
    __syncthreads();
#pragma unroll
    for (int i = 0; i < 4; ++i) {
      int idx = t + i * 256;
      int row = idx >> 3, c4 = (idx & 7) * 4;
      float4 v = *reinterpret_cast<const float4*>(&x[(size_t)(m0 + row) * En + k0 + c4]);
      ushort4 p;
      p.x = f2bf(v.x); p.y = f2bf(v.y); p.z = f2bf(v.z); p.w = f2bf(v.w);
      *reinterpret_cast<ushort4*>(&As[row][c4]) = p;
    }
#pragma unroll
    for (int i = 0; i < 4; ++i) {
      int idx = t + i * 256;
      int kk = idx >> 5, c4 = (idx & 31) * 4;
      float4 v = *reinterpret_cast<const float4*>(&W[(size_t)(k0 + kk) * En + n0 + c4]);
      BsT[c4 + 0][kk] = f2bf(v.x);
      BsT[c4 + 1][kk] = f2bf(v.y);
      BsT[c4 + 2][kk] = f2bf(v.z);
      BsT[c4 + 3][kk] = f2bf(v.w);
    }
    __syncthreads();

    const int koff = (l >> 4) * 8;
    short8 a[4], bfr[4];
#pragma unroll
    for (int m = 0; m < 4; ++m)
      a[m] = *reinterpret_cast<const short8*>(&As[wm * 64 + m * 16 + (l & 15)][koff]);
#pragma unroll
    for (int n = 0; n < 4; ++n)
      bfr[n] = *reinterpret_cast<const short8*>(&BsT[wn * 64 + n * 16 + (l & 15)][koff]);
#pragma unroll
    for (int m = 0; m < 4; ++m)
#pragma unroll
      for (int n = 0; n < 4; ++n)
        acc[m][n] = __builtin_amdgcn_mfma_f32_16x16x32_bf16(a[m], bfr[n], acc[m][n], 0, 0, 0);
  }

#pragma unroll
  for (int m = 0; m < 4; ++m)
#pragma unroll
    for (int n = 0; n < 4; ++n)
#pragma unroll
      for (int j = 0; j < 4; ++j) {
        int row = m0 + wm * 64 + m * 16 + (l >> 4) * 4 + j;
        int col = n0 + wn * 64 + n * 16 + (l & 15);
        int s = row & (Sn - 1);
        float v = acc[m][n][j] + bias[s];
        int b = row >> 11;
        int h = col >> 7, d = col & 127;
        out[(size_t)((b * Hn + h) * Sn + s) * Dn + d] = f2bf(v);
      }
}

// ---------------------------------------------------------------------------
// K1b: V transpose  v[bh][s][d] -> vT[bh][d][s] (unchanged).
// ---------------------------------------------------------------------------
__global__ __launch_bounds__(256) void vtrans_kernel(
    const unsigned short* __restrict__ v, unsigned short* __restrict__ vT) {
  const int s0 = blockIdx.x * 64, d0 = blockIdx.y * 64;
  const int bh = blockIdx.z;
  const unsigned short* vp = v + (size_t)bh * Sn * Dn;
  unsigned short* op = vT + (size_t)bh * Dn * Sn;
  __shared__ unsigned short Ls[64][72];
  const int t = threadIdx.x;
#pragma unroll
  for (int it = 0; it < 2; ++it) {
    int flat = t + it * 256;
    int r = flat >> 3, cc = flat & 7;
    *reinterpret_cast<short8*>(&Ls[r][cc * 8]) =
        *reinterpret_cast<const short8*>(&vp[(size_t)(s0 + r) * Dn + d0 + cc * 8]);
  }
  __syncthreads();
#pragma unroll
  for (int it = 0; it < 2; ++it) {
    int flat = t + it * 256;
    int d = flat >> 3, sc = flat & 7;
    short8 o;
#pragma unroll
    for (int jo = 0; jo < 8; ++jo) {
      int jj = (jo + sc) & 7;
      o[jj] = (short)Ls[sc * 8 + jj][d];
    }
    *reinterpret_cast<short8*>(&op[(size_t)(d0 + d) * Sn + s0 + sc * 8]) = o;
  }
}

// ---------------------------------------------------------------------------
// K2: fused attention v6 — OCCUPANCY build: 4 blocks/CU (16 waves/CU).
// KVBLK=32.  LDS = Kb 16KB + Ps 10KB + red 0.5KB ≈ 27KB; VGPR capped 128.
// Wave (th = w&1, sh = w>>1): QK^T computes t-rows th*16+.., s-rows
// sh*32+.. (Q in regs, 32 VGPR).  PV: wave owns d-cols w*32..+31; V frags
// in REGISTERS prefetched from global vT (no V LDS).  PV lags one tile.
// ---------------------------------------------------------------------------
__global__ __launch_bounds__(256, 4) void fused_attn6_kernel(
    const unsigned short* __restrict__ qkv, const unsigned short* __restrict__ vT,
    const float* __restrict__ Wepi, const float* __restrict__ bo,
    float* __restrict__ attn, float* __restrict__ effect) {
  const int bh = blockIdx.y;
  const int s0 = blockIdx.x * 64;
  const unsigned short* qp = qkv + (size_t)bh * Sn * Dn;
  const unsigned short* kp = qkv + (size_t)(BHn + bh) * Sn * Dn;
  const unsigned short* vt = vT + (size_t)bh * Dn * Sn;

  __shared__ unsigned short Kb[2][32 * 128];   // K tiles [t][d], XOR-swizzled
  __shared__ unsigned short Ps[2][64 * 40];    // P tiles [s][t], row pad->80B
  __shared__ float red[4][2][16];              // cross-wave-pair row sums

  const int t = threadIdx.x, l = t & 63, w = t >> 6;
  const int g = l >> 4, i = l & 15;
  const int th = w & 1;    // t-half of the 32-row K tile
  const int sh = w >> 1;   // s-half of the 64 q rows
  const float scale = 0.022097086912079608f;  // 1/sqrt(2048)

  // Q B-frags for this wave's 32 s-rows (32 VGPR)
  short8 aq[2][4];
#pragma unroll
  for (int sf = 0; sf < 2; ++sf)
#pragma unroll
    for (int ks = 0; ks < 4; ++ks)
      aq[sf][ks] = *reinterpret_cast<const short8*>(
          &qp[(size_t)(s0 + sh * 32 + sf * 16 + i) * Dn + ks * 32 + g * 8]);

  // K staging descriptors: 32x128 tile, 512 chunks, 2 per thread
  int ksrc[2], kdst[2];
#pragma unroll
  for (int it = 0; it < 2; ++it) {
    int flat = t + it * 256;
    int r = flat >> 4, cc = flat & 15;
    ksrc[it] = r * Dn + cc * 8;
    kdst[it] = r * 128 + ((cc ^ (r & 15)) << 3);
  }

  // ---------------- sweep 1: exp row-sums ----------------
  short8 kreg[2];
#pragma unroll
  for (int it = 0; it < 2; ++it)
    kreg[it] = *reinterpret_cast<const short8*>(&kp[ksrc[it]]);
#pragma unroll
  for (int it = 0; it < 2; ++it)
    *reinterpret_cast<short8*>(&Kb[0][kdst[it]]) = kreg[it];
#pragma unroll
  for (int it = 0; it < 2; ++it)
    kreg[it] = *reinterpret_cast<const short8*>(&kp[(size_t)32 * Dn + ksrc[it]]);
  bar_pub();

  float rs[2] = {0.f, 0.f};
  for (int kt = 0; kt < 64; ++kt) {
    const int b = kt & 1;
    f32x4 accT[2] = {};
    __builtin_amdgcn_s_setprio(1);
#pragma unroll
    for (int ks = 0; ks < 4; ++ks) {
      short8 ak = *reinterpret_cast<const short8*>(
          &Kb[b][(th * 16 + i) * 128 + (((ks * 4 + g) ^ i) << 3)]);
#pragma unroll
      for (int sf = 0; sf < 2; ++sf)
        accT[sf] = __builtin_amdgcn_mfma_f32_16x16x32_bf16(ak, aq[sf][ks], accT[sf], 0, 0, 0);
    }
    __builtin_amdgcn_s_setprio(0);
#pragma unroll
    for (int sf = 0; sf < 2; ++sf)
      rs[sf] += __expf(accT[sf][0] * scale) + __expf(accT[sf][1] * scale) +
                __expf(accT[sf][2] * scale) + __expf(accT[sf][3] * scale);
    if (kt < 63) {
#pragma unroll
      for (int it = 0; it < 2; ++it)
        *reinterpret_cast<short8*>(&Kb[b ^ 1][kdst[it]]) = kreg[it];
      if (kt < 62)
#pragma unroll
        for (int it = 0; it < 2; ++it)
          kreg[it] = *reinterpret_cast<const short8*>(
              &kp[(size_t)(kt + 2) * 32 * Dn + ksrc[it]]);
    }
    bar_pub();
  }

  // reduce over g (in-wave) then across the wave pair (th=0/1) via LDS
#pragma unroll
  for (int sf = 0; sf < 2; ++sf) {
    float v = rs[sf];
    v += __shfl_xor(v, 16);
    v += __shfl_xor(v, 32);
    if (l < 16) red[w][sf][l] = v;
  }
  bar_pub();
  float rinv[2];
#pragma unroll
  for (int sf = 0; sf < 2; ++sf)
    rinv[sf] = 1.0f / (red[w][sf][i] + red[w ^ 1][sf][i]);

  // ---------------- sweep 2 prologue ----------------
#pragma unroll
  for (int it = 0; it < 2; ++it)
    kreg[it] = *reinterpret_cast<const short8*>(&kp[ksrc[it]]);
#pragma unroll
  for (int it = 0; it < 2; ++it)
    *reinterpret_cast<short8*>(&Kb[0][kdst[it]]) = kreg[it];
#pragma unroll
  for (int it = 0; it < 2; ++it)
    kreg[it] = *reinterpret_cast<const short8*>(&kp[(size_t)32 * Dn + ksrc[it]]);
  bar_pub();

  // per-lane row pointers (row s = s0 + sh*32 + [sf*16] + i)
  const float* wrow = Wepi + (size_t)(s0 + sh * 32 + i) * Sn + th * 16 + g * 4;
  float* arow = attn + (size_t)bh * Sn * Sn + (size_t)(s0 + sh * 32 + i) * Sn + th * 16 + g * 4;

  f32x4 pv[4][2] = {};
  short8 vreg[2];

  for (int kt = 0; kt < 64; ++kt) {
    const int b = kt & 1;
    const int t0 = kt * 32;
    f32x4 accT[2] = {};
    __builtin_amdgcn_s_setprio(1);
#pragma unroll
    for (int ks = 0; ks < 4; ++ks) {
      short8 ak = *reinterpret_cast<const short8*>(
          &Kb[b][(th * 16 + i) * 128 + (((ks * 4 + g) ^ i) << 3)]);
#pragma unroll
      for (int sf = 0; sf < 2; ++sf)
        accT[sf] = __builtin_amdgcn_mfma_f32_16x16x32_bf16(ak, aq[sf][ks], accT[sf], 0, 0, 0);
    }
    // PV for tile kt-1: Ps[b^1] + vreg (loaded last iteration)
    if (kt > 0) {
#pragma unroll
      for (int pf = 0; pf < 4; ++pf) {
        short8 pa = *reinterpret_cast<const short8*>(&Ps[b ^ 1][(pf * 16 + i) * 40 + g * 8]);
#pragma unroll
        for (int nf = 0; nf < 2; ++nf)
          pv[pf][nf] = __builtin_amdgcn_mfma_f32_16x16x32_bf16(pa, vreg[nf], pv[pf][nf], 0, 0, 0);
      }
    }
    __builtin_amdgcn_s_setprio(0);

    // V frags for tile kt (consumed next iteration); 16B/lane from global vT
#pragma unroll
    for (int nf = 0; nf < 2; ++nf)
      vreg[nf] = *reinterpret_cast<const short8*>(
          &vt[(size_t)(w * 32 + nf * 16 + i) * Sn + t0 + g * 8]);

    // epilogue: p = exp*rinv*Wepi -> attn float4 + Ps bf16 (TLP hides VMEM)
    float4 w4[2];
#pragma unroll
    for (int sf = 0; sf < 2; ++sf)
      w4[sf] = *reinterpret_cast<const float4*>(&wrow[(size_t)sf * 16 * Sn + t0]);
#pragma unroll
    for (int sf = 0; sf < 2; ++sf) {
      float q0 = __expf(accT[sf][0] * scale) * rinv[sf] * w4[sf].x;
      float q1 = __expf(accT[sf][1] * scale) * rinv[sf] * w4[sf].y;
      float q2 = __expf(accT[sf][2] * scale) * rinv[sf] * w4[sf].z;
      float q3 = __expf(accT[sf][3] * scale) * rinv[sf] * w4[sf].w;
      float4 pf4 = {q0, q1, q2, q3};
      *reinterpret_cast<float4*>(&arow[(size_t)sf * 16 * Sn + t0]) = pf4;
      ushort4 pk;
      pk.x = f2bf(q0); pk.y = f2bf(q1); pk.z = f2bf(q2); pk.w = f2bf(q3);
      *reinterpret_cast<ushort4*>(
          &Ps[b][(sh * 32 + sf * 16 + i) * 40 + th * 16 + g * 4]) = pk;
    }

    // stage next K tile; prefetch K for kt+2
    if (kt < 63) {
#pragma unroll
      for (int it = 0; it < 2; ++it)
        *reinterpret_cast<short8*>(&Kb[b ^ 1][kdst[it]]) = kreg[it];
      if (kt < 62)
#pragma unroll
        for (int it = 0; it < 2; ++it)
          kreg[it] = *reinterpret_cast<const short8*>(
              &kp[(size_t)(kt + 2) * 32 * Dn + ksrc[it]]);
    }
    bar_pub();
  }

  // final PV for tile 63 (Ps[1] published by last barrier; vreg = tile 63)
  __builtin_amdgcn_s_setprio(1);
#pragma unroll
  for (int pf = 0; pf < 4; ++pf) {
    short8 pa = *reinterpret_cast<const short8*>(&Ps[1][(pf * 16 + i) * 40 + g * 8]);
#pragma unroll
    for (int nf = 0; nf < 2; ++nf)
      pv[pf][nf] = __builtin_amdgcn_mfma_f32_16x16x32_bf16(pa, vreg[nf], pv[pf][nf], 0, 0, 0);
  }
  __builtin_amdgcn_s_setprio(0);

  // effect = pv + bo : row s = s0 + pf*16 + g*4 + j, col d = w*32 + nf*16 + i
  const int b_ = bh >> 2, h_ = bh & 3;
#pragma unroll
  for (int pf = 0; pf < 4; ++pf)
#pragma unroll
    for (int j = 0; j < 4; ++j) {
      const int row = s0 + pf * 16 + g * 4 + j;
      const float bias = bo[row];
#pragma unroll
      for (int nf = 0; nf < 2; ++nf)
        effect[(size_t)(b_ * Sn + row) * En + h_ * Dn + w * 32 + nf * 16 + i] =
            pv[pf][nf][j] + bias;
    }
}

// ---------------------------------------------------------------------------
extern "C" void kernel_launch(void* const* d_in, const int* in_sizes, int n_in,
                              void* d_out, int out_size, void* d_ws, size_t ws_size,
                              hipStream_t stream) {
  const float* x    = (const float*)d_in[0];
  const float* Wq   = (const float*)d_in[1];
  const float* Wk   = (const float*)d_in[2];
  const float* Wv   = (const float*)d_in[3];
  const float* Wepi = (const float*)d_in[4];
  const float* bq   = (const float*)d_in[5];
  const float* bk   = (const float*)d_in[6];
  const float* bv   = (const float*)d_in[7];
  const float* bo   = (const float*)d_in[8];

  float* effect = (float*)d_out;
  float* attn = effect + (size_t)Bn * Sn * En;              // attn region of d_out
  unsigned short* qkv = (unsigned short*)d_ws;              // q|k|v bf16 (50.3 MB)
  unsigned short* vT = qkv + (size_t)3 * BHn * Sn * Dn;     // v^T bf16 (16.8 MB)

  qkv_kernel<<<dim3(Mqkv / 128, En / 128, 3), 256, 0, stream>>>(x, Wq, Wk, Wv, bq, bk, bv, qkv);
  vtrans_kernel<<<dim3(Sn / 64, Dn / 64, BHn), 256, 0, stream>>>(
      qkv + (size_t)2 * BHn * Sn * Dn, vT);
  fused_attn6_kernel<<<dim3(Sn / 64, BHn), 256, 0, stream>>>(qkv, vT, Wepi, bo, attn, effect);
}

// Round 8
// 457.577 us; speedup vs baseline: 1.0498x; 1.0498x over previous
//
#include <hip/hip_runtime.h>
#include <hip/hip_bf16.h>

// Problem constants
constexpr int Bn = 8, Sn = 2048, En = 512, Hn = 4, Dn = 128;
constexpr int BHn = Bn * Hn;          // 32
constexpr int Mqkv = Bn * Sn;         // 16384

typedef __attribute__((ext_vector_type(8))) short short8;
typedef __attribute__((ext_vector_type(4))) float f32x4;

__device__ __forceinline__ unsigned short f2bf(float f) {
  unsigned int u = __builtin_bit_cast(unsigned int, f);
  u += 0x7FFF + ((u >> 16) & 1);   // round-to-nearest-even
  return (unsigned short)(u >> 16);
}

// publish LDS writes; do NOT drain vmcnt (prefetch loads stay in flight)
__device__ __forceinline__ void bar_pub() {
  asm volatile("s_waitcnt lgkmcnt(0)" ::: "memory");
  __builtin_amdgcn_s_barrier();
  asm volatile("" ::: "memory");
}

// ---------------------------------------------------------------------------
// K1: QKV projection (unchanged).
// ---------------------------------------------------------------------------
__global__ __launch_bounds__(256) void qkv_kernel(
    const float* __restrict__ x, const float* __restrict__ Wq,
    const float* __restrict__ Wk, const float* __restrict__ Wv,
    const float* __restrict__ bq, const float* __restrict__ bk,
    const float* __restrict__ bv, unsigned short* __restrict__ qkv) {
  const int z = blockIdx.z;
  const float* W = (z == 0) ? Wq : (z == 1 ? Wk : Wv);
  const float* bias = (z == 0) ? bq : (z == 1 ? bk : bv);
  unsigned short* out = qkv + (size_t)z * BHn * Sn * Dn;

  __shared__ unsigned short As[128][40];
  __shared__ unsigned short BsT[128][40];

  const int t = threadIdx.x;
  const int l = t & 63, w = t >> 6;
  const int wm = w >> 1, wn = w & 1;
  const int m0 = blockIdx.x * 128, n0 = blockIdx.y * 128;

  f32x4 acc[4][4] = {};

  for (int k0 = 0; k0 < En; k0 += 32) {
    __syncthreads();
#pragma unroll
    for (int i = 0; i < 4; ++i) {
      int idx = t + i * 256;
      int row = idx >> 3, c4 = (idx & 7) * 4;
      float4 v = *reinterpret_cast<const float4*>(&x[(size_t)(m0 + row) * En + k0 + c4]);
      ushort4 p;
      p.x = f2bf(v.x); p.y = f2bf(v.y); p.z = f2bf(v.z); p.w = f2bf(v.w);
      *reinterpret_cast<ushort4*>(&As[row][c4]) = p;
    }
#pragma unroll
    for (int i = 0; i < 4; ++i) {
      int idx = t + i * 256;
      int kk = idx >> 5, c4 = (idx & 31) * 4;
      float4 v = *reinterpret_cast<const float4*>(&W[(size_t)(k0 + kk) * En + n0 + c4]);
      BsT[c4 + 0][kk] = f2bf(v.x);
      BsT[c4 + 1][kk] = f2bf(v.y);
      BsT[c4 + 2][kk] = f2bf(v.z);
      BsT[c4 + 3][kk] = f2bf(v.w);
    }
    __syncthreads();

    const int koff = (l >> 4) * 8;
    short8 a[4], bfr[4];
#pragma unroll
    for (int m = 0; m < 4; ++m)
      a[m] = *reinterpret_cast<const short8*>(&As[wm * 64 + m * 16 + (l & 15)][koff]);
#pragma unroll
    for (int n = 0; n < 4; ++n)
      bfr[n] = *reinterpret_cast<const short8*>(&BsT[wn * 64 + n * 16 + (l & 15)][koff]);
#pragma unroll
    for (int m = 0; m < 4; ++m)
#pragma unroll
      for (int n = 0; n < 4; ++n)
        acc[m][n] = __builtin_amdgcn_mfma_f32_16x16x32_bf16(a[m], bfr[n], acc[m][n], 0, 0, 0);
  }

#pragma unroll
  for (int m = 0; m < 4; ++m)
#pragma unroll
    for (int n = 0; n < 4; ++n)
#pragma unroll
      for (int j = 0; j < 4; ++j) {
        int row = m0 + wm * 64 + m * 16 + (l >> 4) * 4 + j;
        int col = n0 + wn * 64 + n * 16 + (l & 15);
        int s = row & (Sn - 1);
        float v = acc[m][n][j] + bias[s];
        int b = row >> 11;
        int h = col >> 7, d = col & 127;
        out[(size_t)((b * Hn + h) * Sn + s) * Dn + d] = f2bf(v);
      }
}

// ---------------------------------------------------------------------------
// K1b: V transpose  v[bh][s][d] -> vT[bh][d][s] (unchanged).
// ---------------------------------------------------------------------------
__global__ __launch_bounds__(256) void vtrans_kernel(
    const unsigned short* __restrict__ v, unsigned short* __restrict__ vT) {
  const int s0 = blockIdx.x * 64, d0 = blockIdx.y * 64;
  const int bh = blockIdx.z;
  const unsigned short* vp = v + (size_t)bh * Sn * Dn;
  unsigned short* op = vT + (size_t)bh * Dn * Sn;
  __shared__ unsigned short Ls[64][72];
  const int t = threadIdx.x;
#pragma unroll
  for (int it = 0; it < 2; ++it) {
    int flat = t + it * 256;
    int r = flat >> 3, cc = flat & 7;
    *reinterpret_cast<short8*>(&Ls[r][cc * 8]) =
        *reinterpret_cast<const short8*>(&vp[(size_t)(s0 + r) * Dn + d0 + cc * 8]);
  }
  __syncthreads();
#pragma unroll
  for (int it = 0; it < 2; ++it) {
    int flat = t + it * 256;
    int d = flat >> 3, sc = flat & 7;
    short8 o;
#pragma unroll
    for (int jo = 0; jo < 8; ++jo) {
      int jj = (jo + sc) & 7;
      o[jj] = (short)Ls[sc * 8 + jj][d];
    }
    *reinterpret_cast<short8*>(&op[(size_t)(d0 + d) * Sn + s0 + sc * 8]) = o;
  }
}

// ---------------------------------------------------------------------------
// K2: fused attention v7 — COALESCED epilogue build.
// Theory: prior versions were VMEM-transaction-bound (per-lane-row scatter on
// attn stores / Wepi loads / V loads = 64 cache lines per wave-instr).
// v7 routes the score tile through LDS and does all global I/O in a
// coalesced thread mapping (thread t -> row t/8, cols (t%8)*4).
// KVBLK=32, 64 tiles; LDS = Kb 16K + Vs 10K + Sf 9K(+invl pad) + Ps 5K
// = 40960 B exactly -> 4 blocks/CU; VGPR capped 128.
// ---------------------------------------------------------------------------
__global__ __launch_bounds__(256, 4) void fused_attn7_kernel(
    const unsigned short* __restrict__ qkv, const unsigned short* __restrict__ vT,
    const float* __restrict__ Wepi, const float* __restrict__ bo,
    float* __restrict__ attn, float* __restrict__ effect) {
  const int bh = blockIdx.y;
  const int s0 = blockIdx.x * 64;
  const unsigned short* qp = qkv + (size_t)bh * Sn * Dn;
  const unsigned short* kp = qkv + (size_t)(BHn + bh) * Sn * Dn;
  const unsigned short* vt = vT + (size_t)bh * Dn * Sn;

  __shared__ unsigned short Kb[2][32 * 128];  // K tiles [t][d], XOR-swizzled
  __shared__ unsigned short Vs[128 * 40];     // V^T tile [d][t], padded
  __shared__ float Sf[64 * 36];               // scores [s][t-local]; col 32 = invl
  __shared__ unsigned short Ps[64 * 40];      // P bf16 [s][t]; sweep1: red (float)

  const int t = threadIdx.x, l = t & 63, w = t >> 6;
  const int g = l >> 4, i = l & 15;
  const int th = w & 1, sh = w >> 1;
  const float scale = 0.022097086912079608f;  // 1/sqrt(2048)

  // Q B-frags for this wave's 32 s-rows (32 VGPR)
  short8 aq[2][4];
#pragma unroll
  for (int sf = 0; sf < 2; ++sf)
#pragma unroll
    for (int ks = 0; ks < 4; ++ks)
      aq[sf][ks] = *reinterpret_cast<const short8*>(
          &qp[(size_t)(s0 + sh * 32 + sf * 16 + i) * Dn + ks * 32 + g * 8]);

  // staging descriptors (coalesced global, swizzled/padded LDS)
  int ksrc[2], kdst[2], vsrc[2], vdst[2];
#pragma unroll
  for (int it = 0; it < 2; ++it) {
    int flat = t + it * 256;
    int r = flat >> 4, cc = flat & 15;   // K tile: 32 rows x 16 chunks
    ksrc[it] = r * Dn + cc * 8;
    kdst[it] = r * 128 + ((cc ^ (r & 15)) << 3);
    int dr = flat >> 2, t8 = (flat & 3) * 8;  // V tile: 128 rows x 4 chunks
    vsrc[it] = dr * Sn + t8;
    vdst[it] = dr * 40 + t8;
  }

  // coalesced-phase mapping: chunk0 = t -> row sr, cols cc4; chunk1 row sr+32
  const int sr = t >> 3, cc4 = (t & 7) * 4;

  // ---------------- sweep 1: exp row-sums ----------------
  short8 kreg[2];
#pragma unroll
  for (int it = 0; it < 2; ++it)
    kreg[it] = *reinterpret_cast<const short8*>(&kp[ksrc[it]]);
#pragma unroll
  for (int it = 0; it < 2; ++it)
    *reinterpret_cast<short8*>(&Kb[0][kdst[it]]) = kreg[it];
#pragma unroll
  for (int it = 0; it < 2; ++it)
    kreg[it] = *reinterpret_cast<const short8*>(&kp[(size_t)32 * Dn + ksrc[it]]);
  bar_pub();

  float rs[2] = {0.f, 0.f};
  for (int kt = 0; kt < 64; ++kt) {
    const int b = kt & 1;
    f32x4 accT[2] = {};
    __builtin_amdgcn_s_setprio(1);
#pragma unroll
    for (int ks = 0; ks < 4; ++ks) {
      short8 ak = *reinterpret_cast<const short8*>(
          &Kb[b][(th * 16 + i) * 128 + (((ks * 4 + g) ^ i) << 3)]);
#pragma unroll
      for (int sf = 0; sf < 2; ++sf)
        accT[sf] = __builtin_amdgcn_mfma_f32_16x16x32_bf16(ak, aq[sf][ks], accT[sf], 0, 0, 0);
    }
    __builtin_amdgcn_s_setprio(0);
#pragma unroll
    for (int sf = 0; sf < 2; ++sf)
      rs[sf] += __expf(accT[sf][0] * scale) + __expf(accT[sf][1] * scale) +
                __expf(accT[sf][2] * scale) + __expf(accT[sf][3] * scale);
    if (kt < 63) {
#pragma unroll
      for (int it = 0; it < 2; ++it)
        *reinterpret_cast<short8*>(&Kb[b ^ 1][kdst[it]]) = kreg[it];
      if (kt < 62)
#pragma unroll
        for (int it = 0; it < 2; ++it)
          kreg[it] = *reinterpret_cast<const short8*>(
              &kp[(size_t)(kt + 2) * 32 * Dn + ksrc[it]]);
    }
    bar_pub();
  }

  // reduce: in-wave over g, cross wave-pair via red (overlaid on Ps)
  float* red = reinterpret_cast<float*>(Ps);
#pragma unroll
  for (int sf = 0; sf < 2; ++sf) {
    float v = rs[sf];
    v += __shfl_xor(v, 16);
    v += __shfl_xor(v, 32);
    if (l < 16) red[w * 32 + sf * 16 + l] = v;
  }
  bar_pub();
  if (g == 0 && th == 0) {
#pragma unroll
    for (int sf = 0; sf < 2; ++sf) {
      const int s = sh * 32 + sf * 16 + i;
      float sum = red[w * 32 + sf * 16 + i] + red[(w ^ 1) * 32 + sf * 16 + i];
      Sf[s * 36 + 32] = 1.0f / sum;   // invl in Sf pad column
    }
  }

  // ---------------- sweep 2 prologue ----------------
  short8 vld[2];
#pragma unroll
  for (int it = 0; it < 2; ++it)
    kreg[it] = *reinterpret_cast<const short8*>(&kp[ksrc[it]]);
#pragma unroll
  for (int it = 0; it < 2; ++it)
    *reinterpret_cast<short8*>(&Kb[0][kdst[it]]) = kreg[it];
#pragma unroll
  for (int it = 0; it < 2; ++it) {
    kreg[it] = *reinterpret_cast<const short8*>(&kp[(size_t)32 * Dn + ksrc[it]]);
    vld[it] = *reinterpret_cast<const short8*>(&vt[vsrc[it]]);
  }
  bar_pub();   // publishes Kb[0] + invl

  float* attnb = attn + (size_t)bh * Sn * Sn;
  const float* wp0 = Wepi + (size_t)(s0 + sr) * Sn + cc4;
  const float* wp1 = Wepi + (size_t)(s0 + sr + 32) * Sn + cc4;
  float* ap0 = attnb + (size_t)(s0 + sr) * Sn + cc4;
  float* ap1 = attnb + (size_t)(s0 + sr + 32) * Sn + cc4;

  f32x4 pv[4][2] = {};
  for (int kt = 0; kt < 64; ++kt) {
    const int b = kt & 1;
    const int t0 = kt * 32;
    // issue Wepi loads FIRST (oldest in vmcnt queue -> later prefetches
    // don't get drained when these are consumed)
    float4 wq0 = *reinterpret_cast<const float4*>(&wp0[t0]);
    float4 wq1 = *reinterpret_cast<const float4*>(&wp1[t0]);

    f32x4 accT[2] = {};
    __builtin_amdgcn_s_setprio(1);
#pragma unroll
    for (int ks = 0; ks < 4; ++ks) {
      short8 ak = *reinterpret_cast<const short8*>(
          &Kb[b][(th * 16 + i) * 128 + (((ks * 4 + g) ^ i) << 3)]);
#pragma unroll
      for (int sf = 0; sf < 2; ++sf)
        accT[sf] = __builtin_amdgcn_mfma_f32_16x16x32_bf16(ak, aq[sf][ks], accT[sf], 0, 0, 0);
    }
    // PV for tile kt-1 (Ps/Vs hold tile kt-1; barrier'd last iteration)
    if (kt > 0) {
#pragma unroll
      for (int pf = 0; pf < 4; ++pf) {
        short8 pa = *reinterpret_cast<const short8*>(&Ps[(pf * 16 + i) * 40 + g * 8]);
#pragma unroll
        for (int nf = 0; nf < 2; ++nf) {
          const int d = w * 32 + nf * 16 + i;
          short8 bv = *reinterpret_cast<const short8*>(&Vs[d * 40 + g * 8]);
          pv[pf][nf] = __builtin_amdgcn_mfma_f32_16x16x32_bf16(pa, bv, pv[pf][nf], 0, 0, 0);
        }
      }
    }
    __builtin_amdgcn_s_setprio(0);

    // write raw scores to Sf (per-lane layout; LDS absorbs the scatter)
#pragma unroll
    for (int sf = 0; sf < 2; ++sf)
      *reinterpret_cast<f32x4*>(
          &Sf[(sh * 32 + sf * 16 + i) * 36 + th * 16 + g * 4]) = accT[sf];
    bar_pub();   // Sf visible; all PV reads of Ps/Vs retired

    // stage next K tile + THIS tile's V (PV reads it next iteration)
    if (kt < 63)
#pragma unroll
      for (int it = 0; it < 2; ++it)
        *reinterpret_cast<short8*>(&Kb[b ^ 1][kdst[it]]) = kreg[it];
#pragma unroll
    for (int it = 0; it < 2; ++it)
      *reinterpret_cast<short8*>(&Vs[vdst[it]]) = vld[it];
    if (kt < 62)
#pragma unroll
      for (int it = 0; it < 2; ++it)
        kreg[it] = *reinterpret_cast<const short8*>(
            &kp[(size_t)(kt + 2) * 32 * Dn + ksrc[it]]);
    if (kt < 63)
#pragma unroll
      for (int it = 0; it < 2; ++it)
        vld[it] = *reinterpret_cast<const short8*>(&vt[t0 + 32 + vsrc[it]]);

    // coalesced epilogue: thread t -> rows sr, sr+32; cols cc4..cc4+3
    {
      float4 s4 = *reinterpret_cast<const float4*>(&Sf[sr * 36 + cc4]);
      float iv0 = Sf[sr * 36 + 32];
      float4 o0;
      o0.x = __expf(s4.x * scale) * iv0 * wq0.x;
      o0.y = __expf(s4.y * scale) * iv0 * wq0.y;
      o0.z = __expf(s4.z * scale) * iv0 * wq0.z;
      o0.w = __expf(s4.w * scale) * iv0 * wq0.w;
      *reinterpret_cast<float4*>(&ap0[t0]) = o0;
      ushort4 pk0;
      pk0.x = f2bf(o0.x); pk0.y = f2bf(o0.y); pk0.z = f2bf(o0.z); pk0.w = f2bf(o0.w);
      *reinterpret_cast<ushort4*>(&Ps[sr * 40 + cc4]) = pk0;

      float4 s5 = *reinterpret_cast<const float4*>(&Sf[(sr + 32) * 36 + cc4]);
      float iv1 = Sf[(sr + 32) * 36 + 32];
      float4 o1;
      o1.x = __expf(s5.x * scale) * iv1 * wq1.x;
      o1.y = __expf(s5.y * scale) * iv1 * wq1.y;
      o1.z = __expf(s5.z * scale) * iv1 * wq1.z;
      o1.w = __expf(s5.w * scale) * iv1 * wq1.w;
      *reinterpret_cast<float4*>(&ap1[t0]) = o1;
      ushort4 pk1;
      pk1.x = f2bf(o1.x); pk1.y = f2bf(o1.y); pk1.z = f2bf(o1.z); pk1.w = f2bf(o1.w);
      *reinterpret_cast<ushort4*>(&Ps[(sr + 32) * 40 + cc4]) = pk1;
    }
    bar_pub();   // Ps/Vs (tile kt) visible for next iteration's PV
  }

  // final PV for tile 63
  __builtin_amdgcn_s_setprio(1);
#pragma unroll
  for (int pf = 0; pf < 4; ++pf) {
    short8 pa = *reinterpret_cast<const short8*>(&Ps[(pf * 16 + i) * 40 + g * 8]);
#pragma unroll
    for (int nf = 0; nf < 2; ++nf) {
      const int d = w * 32 + nf * 16 + i;
      short8 bv = *reinterpret_cast<const short8*>(&Vs[d * 40 + g * 8]);
      pv[pf][nf] = __builtin_amdgcn_mfma_f32_16x16x32_bf16(pa, bv, pv[pf][nf], 0, 0, 0);
    }
  }
  __builtin_amdgcn_s_setprio(0);

  // effect = pv + bo : row s = s0 + pf*16 + g*4 + j, col d = w*32 + nf*16 + i
  const int b_ = bh >> 2, h_ = bh & 3;
#pragma unroll
  for (int pf = 0; pf < 4; ++pf)
#pragma unroll
    for (int j = 0; j < 4; ++j) {
      const int row = s0 + pf * 16 + g * 4 + j;
      const float bias = bo[row];
#pragma unroll
      for (int nf = 0; nf < 2; ++nf)
        effect[(size_t)(b_ * Sn + row) * En + h_ * Dn + w * 32 + nf * 16 + i] =
            pv[pf][nf][j] + bias;
    }
}

// ---------------------------------------------------------------------------
extern "C" void kernel_launch(void* const* d_in, const int* in_sizes, int n_in,
                              void* d_out, int out_size, void* d_ws, size_t ws_size,
                              hipStream_t stream) {
  const float* x    = (const float*)d_in[0];
  const float* Wq   = (const float*)d_in[1];
  const float* Wk   = (const float*)d_in[2];
  const float* Wv   = (const float*)d_in[3];
  const float* Wepi = (const float*)d_in[4];
  const float* bq   = (const float*)d_in[5];
  const float* bk   = (const float*)d_in[6];
  const float* bv   = (const float*)d_in[7];
  const float* bo   = (const float*)d_in[8];

  float* effect = (float*)d_out;
  float* attn = effect + (size_t)Bn * Sn * En;              // attn region of d_out
  unsigned short* qkv = (unsigned short*)d_ws;              // q|k|v bf16 (50.3 MB)
  unsigned short* vT = qkv + (size_t)3 * BHn * Sn * Dn;     // v^T bf16 (16.8 MB)

  qkv_kernel<<<dim3(Mqkv / 128, En / 128, 3), 256, 0, stream>>>(x, Wq, Wk, Wv, bq, bk, bv, qkv);
  vtrans_kernel<<<dim3(Sn / 64, Dn / 64, BHn), 256, 0, stream>>>(
      qkv + (size_t)2 * BHn * Sn * Dn, vT);
  fused_attn7_kernel<<<dim3(Sn / 64, BHn), 256, 0, stream>>>(qkv, vT, Wepi, bo, attn, effect);
}

// Round 10
// 348.357 us; speedup vs baseline: 1.3790x; 1.3135x over previous
//
#include <hip/hip_runtime.h>
#include <hip/hip_bf16.h>

// Problem constants
constexpr int Bn = 8, Sn = 2048, En = 512, Hn = 4, Dn = 128;
constexpr int BHn = Bn * Hn;          // 32
constexpr int Mqkv = Bn * Sn;         // 16384

typedef __attribute__((ext_vector_type(8))) short short8;
typedef __attribute__((ext_vector_type(4))) float f32x4;

__device__ __forceinline__ unsigned short f2bf(float f) {
  unsigned int u = __builtin_bit_cast(unsigned int, f);
  u += 0x7FFF + ((u >> 16) & 1);   // round-to-nearest-even
  return (unsigned short)(u >> 16);
}

// publish LDS writes; do NOT drain vmcnt (prefetch loads stay in flight)
__device__ __forceinline__ void bar_pub() {
  asm volatile("s_waitcnt lgkmcnt(0)" ::: "memory");
  __builtin_amdgcn_s_barrier();
  asm volatile("" ::: "memory");
}

// ---------------------------------------------------------------------------
// K1: QKV projection (unchanged).
// ---------------------------------------------------------------------------
__global__ __launch_bounds__(256) void qkv_kernel(
    const float* __restrict__ x, const float* __restrict__ Wq,
    const float* __restrict__ Wk, const float* __restrict__ Wv,
    const float* __restrict__ bq, const float* __restrict__ bk,
    const float* __restrict__ bv, unsigned short* __restrict__ qkv) {
  const int z = blockIdx.z;
  const float* W = (z == 0) ? Wq : (z == 1 ? Wk : Wv);
  const float* bias = (z == 0) ? bq : (z == 1 ? bk : bv);
  unsigned short* out = qkv + (size_t)z * BHn * Sn * Dn;

  __shared__ unsigned short As[128][40];
  __shared__ unsigned short BsT[128][40];

  const int t = threadIdx.x;
  const int l = t & 63, w = t >> 6;
  const int wm = w >> 1, wn = w & 1;
  const int m0 = blockIdx.x * 128, n0 = blockIdx.y * 128;

  f32x4 acc[4][4] = {};

  for (int k0 = 0; k0 < En; k0 += 32) {
    __syncthreads();
#pragma unroll
    for (int i = 0; i < 4; ++i) {
      int idx = t + i * 256;
      int row = idx >> 3, c4 = (idx & 7) * 4;
      float4 v = *reinterpret_cast<const float4*>(&x[(size_t)(m0 + row) * En + k0 + c4]);
      ushort4 p;
      p.x = f2bf(v.x); p.y = f2bf(v.y); p.z = f2bf(v.z); p.w = f2bf(v.w);
      *reinterpret_cast<ushort4*>(&As[row][c4]) = p;
    }
#pragma unroll
    for (int i = 0; i < 4; ++i) {
      int idx = t + i * 256;
      int kk = idx >> 5, c4 = (idx & 31) * 4;
      float4 v = *reinterpret_cast<const float4*>(&W[(size_t)(k0 + kk) * En + n0 + c4]);
      BsT[c4 + 0][kk] = f2bf(v.x);
      BsT[c4 + 1][kk] = f2bf(v.y);
      BsT[c4 + 2][kk] = f2bf(v.z);
      BsT[c4 + 3][kk] = f2bf(v.w);
    }
    __syncthreads();

    const int koff = (l >> 4) * 8;
    short8 a[4], bfr[4];
#pragma unroll
    for (int m = 0; m < 4; ++m)
      a[m] = *reinterpret_cast<const short8*>(&As[wm * 64 + m * 16 + (l & 15)][koff]);
#pragma unroll
    for (int n = 0; n < 4; ++n)
      bfr[n] = *reinterpret_cast<const short8*>(&BsT[wn * 64 + n * 16 + (l & 15)][koff]);
#pragma unroll
    for (int m = 0; m < 4; ++m)
#pragma unroll
      for (int n = 0; n < 4; ++n)
        acc[m][n] = __builtin_amdgcn_mfma_f32_16x16x32_bf16(a[m], bfr[n], acc[m][n], 0, 0, 0);
  }

#pragma unroll
  for (int m = 0; m < 4; ++m)
#pragma unroll
    for (int n = 0; n < 4; ++n)
#pragma unroll
      for (int j = 0; j < 4; ++j) {
        int row = m0 + wm * 64 + m * 16 + (l >> 4) * 4 + j;
        int col = n0 + wn * 64 + n * 16 + (l & 15);
        int s = row & (Sn - 1);
        float v = acc[m][n][j] + bias[s];
        int b = row >> 11;
        int h = col >> 7, d = col & 127;
        out[(size_t)((b * Hn + h) * Sn + s) * Dn + d] = f2bf(v);
      }
}

// ---------------------------------------------------------------------------
// K1b: V transpose  v[bh][s][d] -> vT[bh][d][s] (unchanged).
// ---------------------------------------------------------------------------
__global__ __launch_bounds__(256) void vtrans_kernel(
    const unsigned short* __restrict__ v, unsigned short* __restrict__ vT) {
  const int s0 = blockIdx.x * 64, d0 = blockIdx.y * 64;
  const int bh = blockIdx.z;
  const unsigned short* vp = v + (size_t)bh * Sn * Dn;
  unsigned short* op = vT + (size_t)bh * Dn * Sn;
  __shared__ unsigned short Ls[64][72];
  const int t = threadIdx.x;
#pragma unroll
  for (int it = 0; it < 2; ++it) {
    int flat = t + it * 256;
    int r = flat >> 3, cc = flat & 7;
    *reinterpret_cast<short8*>(&Ls[r][cc * 8]) =
        *reinterpret_cast<const short8*>(&vp[(size_t)(s0 + r) * Dn + d0 + cc * 8]);
  }
  __syncthreads();
#pragma unroll
  for (int it = 0; it < 2; ++it) {
    int flat = t + it * 256;
    int d = flat >> 3, sc = flat & 7;
    short8 o;
#pragma unroll
    for (int jo = 0; jo < 8; ++jo) {
      int jj = (jo + sc) & 7;
      o[jj] = (short)Ls[sc * 8 + jj][d];
    }
    *reinterpret_cast<short8*>(&op[(size_t)(d0 + d) * Sn + s0 + sc * 8]) = o;
  }
}

// ---------------------------------------------------------------------------
// K2: fused attention v8 = v7 + (a) NON-TEMPORAL attn/effect stores so the
// 536MB streaming write doesn't flush Wepi/K/V out of L2/L3, and
// (b) XCD-aware block swizzle: 1-D grid 1024, id%8 -> XCD; each XCD owns
// 4 s0-values x all 32 bh, so the 32 blocks sharing Wepi rows co-reside on
// one XCD (Wepi working set 2MB < 4MB L2).
// ---------------------------------------------------------------------------
__global__ __launch_bounds__(256, 4) void fused_attn8_kernel(
    const unsigned short* __restrict__ qkv, const unsigned short* __restrict__ vT,
    const float* __restrict__ Wepi, const float* __restrict__ bo,
    float* __restrict__ attn, float* __restrict__ effect) {
  // swizzle: XCD k (= id%8) gets s0-index 4k + (id/8)%4, bh = id/32
  const int id = blockIdx.x;
  const int s0 = ((id & 7) * 4 + ((id >> 3) & 3)) * 64;
  const int bh = id >> 5;

  const unsigned short* qp = qkv + (size_t)bh * Sn * Dn;
  const unsigned short* kp = qkv + (size_t)(BHn + bh) * Sn * Dn;
  const unsigned short* vt = vT + (size_t)bh * Dn * Sn;

  __shared__ unsigned short Kb[2][32 * 128];  // K tiles [t][d], XOR-swizzled
  __shared__ unsigned short Vs[128 * 40];     // V^T tile [d][t], padded
  __shared__ float Sf[64 * 36];               // scores [s][t-local]; col 32 = invl
  __shared__ unsigned short Ps[64 * 40];      // P bf16 [s][t]; sweep1: red (float)

  const int t = threadIdx.x, l = t & 63, w = t >> 6;
  const int g = l >> 4, i = l & 15;
  const int th = w & 1, sh = w >> 1;
  const float scale = 0.022097086912079608f;  // 1/sqrt(2048)

  // Q B-frags for this wave's 32 s-rows (32 VGPR)
  short8 aq[2][4];
#pragma unroll
  for (int sf = 0; sf < 2; ++sf)
#pragma unroll
    for (int ks = 0; ks < 4; ++ks)
      aq[sf][ks] = *reinterpret_cast<const short8*>(
          &qp[(size_t)(s0 + sh * 32 + sf * 16 + i) * Dn + ks * 32 + g * 8]);

  // staging descriptors (coalesced global, swizzled/padded LDS)
  int ksrc[2], kdst[2], vsrc[2], vdst[2];
#pragma unroll
  for (int it = 0; it < 2; ++it) {
    int flat = t + it * 256;
    int r = flat >> 4, cc = flat & 15;   // K tile: 32 rows x 16 chunks
    ksrc[it] = r * Dn + cc * 8;
    kdst[it] = r * 128 + ((cc ^ (r & 15)) << 3);
    int dr = flat >> 2, t8 = (flat & 3) * 8;  // V tile: 128 rows x 4 chunks
    vsrc[it] = dr * Sn + t8;
    vdst[it] = dr * 40 + t8;
  }

  // coalesced-phase mapping: thread t -> row sr (and sr+32), cols cc4
  const int sr = t >> 3, cc4 = (t & 7) * 4;

  // ---------------- sweep 1: exp row-sums ----------------
  short8 kreg[2];
#pragma unroll
  for (int it = 0; it < 2; ++it)
    kreg[it] = *reinterpret_cast<const short8*>(&kp[ksrc[it]]);
#pragma unroll
  for (int it = 0; it < 2; ++it)
    *reinterpret_cast<short8*>(&Kb[0][kdst[it]]) = kreg[it];
#pragma unroll
  for (int it = 0; it < 2; ++it)
    kreg[it] = *reinterpret_cast<const short8*>(&kp[(size_t)32 * Dn + ksrc[it]]);
  bar_pub();

  float rs[2] = {0.f, 0.f};
  for (int kt = 0; kt < 64; ++kt) {
    const int b = kt & 1;
    f32x4 accT[2] = {};
    __builtin_amdgcn_s_setprio(1);
#pragma unroll
    for (int ks = 0; ks < 4; ++ks) {
      short8 ak = *reinterpret_cast<const short8*>(
          &Kb[b][(th * 16 + i) * 128 + (((ks * 4 + g) ^ i) << 3)]);
#pragma unroll
      for (int sf = 0; sf < 2; ++sf)
        accT[sf] = __builtin_amdgcn_mfma_f32_16x16x32_bf16(ak, aq[sf][ks], accT[sf], 0, 0, 0);
    }
    __builtin_amdgcn_s_setprio(0);
#pragma unroll
    for (int sf = 0; sf < 2; ++sf)
      rs[sf] += __expf(accT[sf][0] * scale) + __expf(accT[sf][1] * scale) +
                __expf(accT[sf][2] * scale) + __expf(accT[sf][3] * scale);
    if (kt < 63) {
#pragma unroll
      for (int it = 0; it < 2; ++it)
        *reinterpret_cast<short8*>(&Kb[b ^ 1][kdst[it]]) = kreg[it];
      if (kt < 62)
#pragma unroll
        for (int it = 0; it < 2; ++it)
          kreg[it] = *reinterpret_cast<const short8*>(
              &kp[(size_t)(kt + 2) * 32 * Dn + ksrc[it]]);
    }
    bar_pub();
  }

  // reduce: in-wave over g, cross wave-pair via red (overlaid on Ps)
  float* red = reinterpret_cast<float*>(Ps);
#pragma unroll
  for (int sf = 0; sf < 2; ++sf) {
    float v = rs[sf];
    v += __shfl_xor(v, 16);
    v += __shfl_xor(v, 32);
    if (l < 16) red[w * 32 + sf * 16 + l] = v;
  }
  bar_pub();
  if (g == 0 && th == 0) {
#pragma unroll
    for (int sf = 0; sf < 2; ++sf) {
      const int s = sh * 32 + sf * 16 + i;
      float sum = red[w * 32 + sf * 16 + i] + red[(w ^ 1) * 32 + sf * 16 + i];
      Sf[s * 36 + 32] = 1.0f / sum;   // invl in Sf pad column
    }
  }

  // ---------------- sweep 2 prologue ----------------
  short8 vld[2];
#pragma unroll
  for (int it = 0; it < 2; ++it)
    kreg[it] = *reinterpret_cast<const short8*>(&kp[ksrc[it]]);
#pragma unroll
  for (int it = 0; it < 2; ++it)
    *reinterpret_cast<short8*>(&Kb[0][kdst[it]]) = kreg[it];
#pragma unroll
  for (int it = 0; it < 2; ++it) {
    kreg[it] = *reinterpret_cast<const short8*>(&kp[(size_t)32 * Dn + ksrc[it]]);
    vld[it] = *reinterpret_cast<const short8*>(&vt[vsrc[it]]);
  }
  bar_pub();   // publishes Kb[0] + invl

  float* attnb = attn + (size_t)bh * Sn * Sn;
  const float* wp0 = Wepi + (size_t)(s0 + sr) * Sn + cc4;
  const float* wp1 = Wepi + (size_t)(s0 + sr + 32) * Sn + cc4;
  float* ap0 = attnb + (size_t)(s0 + sr) * Sn + cc4;
  float* ap1 = attnb + (size_t)(s0 + sr + 32) * Sn + cc4;

  f32x4 pv[4][2] = {};
  for (int kt = 0; kt < 64; ++kt) {
    const int b = kt & 1;
    const int t0 = kt * 32;
    // issue Wepi loads FIRST (oldest in vmcnt queue)
    float4 wq0 = *reinterpret_cast<const float4*>(&wp0[t0]);
    float4 wq1 = *reinterpret_cast<const float4*>(&wp1[t0]);

    f32x4 accT[2] = {};
    __builtin_amdgcn_s_setprio(1);
#pragma unroll
    for (int ks = 0; ks < 4; ++ks) {
      short8 ak = *reinterpret_cast<const short8*>(
          &Kb[b][(th * 16 + i) * 128 + (((ks * 4 + g) ^ i) << 3)]);
#pragma unroll
      for (int sf = 0; sf < 2; ++sf)
        accT[sf] = __builtin_amdgcn_mfma_f32_16x16x32_bf16(ak, aq[sf][ks], accT[sf], 0, 0, 0);
    }
    // PV for tile kt-1 (Ps/Vs hold tile kt-1; barrier'd last iteration)
    if (kt > 0) {
#pragma unroll
      for (int pf = 0; pf < 4; ++pf) {
        short8 pa = *reinterpret_cast<const short8*>(&Ps[(pf * 16 + i) * 40 + g * 8]);
#pragma unroll
        for (int nf = 0; nf < 2; ++nf) {
          const int d = w * 32 + nf * 16 + i;
          short8 bv = *reinterpret_cast<const short8*>(&Vs[d * 40 + g * 8]);
          pv[pf][nf] = __builtin_amdgcn_mfma_f32_16x16x32_bf16(pa, bv, pv[pf][nf], 0, 0, 0);
        }
      }
    }
    __builtin_amdgcn_s_setprio(0);

    // write raw scores to Sf (per-lane layout; LDS absorbs the scatter)
#pragma unroll
    for (int sf = 0; sf < 2; ++sf)
      *reinterpret_cast<f32x4*>(
          &Sf[(sh * 32 + sf * 16 + i) * 36 + th * 16 + g * 4]) = accT[sf];
    bar_pub();   // Sf visible; all PV reads of Ps/Vs retired

    // stage next K tile + THIS tile's V (PV reads it next iteration)
    if (kt < 63)
#pragma unroll
      for (int it = 0; it < 2; ++it)
        *reinterpret_cast<short8*>(&Kb[b ^ 1][kdst[it]]) = kreg[it];
#pragma unroll
    for (int it = 0; it < 2; ++it)
      *reinterpret_cast<short8*>(&Vs[vdst[it]]) = vld[it];
    if (kt < 62)
#pragma unroll
      for (int it = 0; it < 2; ++it)
        kreg[it] = *reinterpret_cast<const short8*>(
            &kp[(size_t)(kt + 2) * 32 * Dn + ksrc[it]]);
    if (kt < 63)
#pragma unroll
      for (int it = 0; it < 2; ++it)
        vld[it] = *reinterpret_cast<const short8*>(&vt[t0 + 32 + vsrc[it]]);

    // coalesced epilogue: thread t -> rows sr, sr+32; cols cc4..cc4+3
    {
      float4 s4 = *reinterpret_cast<const float4*>(&Sf[sr * 36 + cc4]);
      float iv0 = Sf[sr * 36 + 32];
      f32x4 o0;
      o0[0] = __expf(s4.x * scale) * iv0 * wq0.x;
      o0[1] = __expf(s4.y * scale) * iv0 * wq0.y;
      o0[2] = __expf(s4.z * scale) * iv0 * wq0.z;
      o0[3] = __expf(s4.w * scale) * iv0 * wq0.w;
      __builtin_nontemporal_store(o0, reinterpret_cast<f32x4*>(&ap0[t0]));
      ushort4 pk0;
      pk0.x = f2bf(o0[0]); pk0.y = f2bf(o0[1]); pk0.z = f2bf(o0[2]); pk0.w = f2bf(o0[3]);
      *reinterpret_cast<ushort4*>(&Ps[sr * 40 + cc4]) = pk0;

      float4 s5 = *reinterpret_cast<const float4*>(&Sf[(sr + 32) * 36 + cc4]);
      float iv1 = Sf[(sr + 32) * 36 + 32];
      f32x4 o1;
      o1[0] = __expf(s5.x * scale) * iv1 * wq1.x;
      o1[1] = __expf(s5.y * scale) * iv1 * wq1.y;
      o1[2] = __expf(s5.z * scale) * iv1 * wq1.z;
      o1[3] = __expf(s5.w * scale) * iv1 * wq1.w;
      __builtin_nontemporal_store(o1, reinterpret_cast<f32x4*>(&ap1[t0]));
      ushort4 pk1;
      pk1.x = f2bf(o1[0]); pk1.y = f2bf(o1[1]); pk1.z = f2bf(o1[2]); pk1.w = f2bf(o1[3]);
      *reinterpret_cast<ushort4*>(&Ps[(sr + 32) * 40 + cc4]) = pk1;
    }
    bar_pub();   // Ps/Vs (tile kt) visible for next iteration's PV
  }

  // final PV for tile 63
  __builtin_amdgcn_s_setprio(1);
#pragma unroll
  for (int pf = 0; pf < 4; ++pf) {
    short8 pa = *reinterpret_cast<const short8*>(&Ps[(pf * 16 + i) * 40 + g * 8]);
#pragma unroll
    for (int nf = 0; nf < 2; ++nf) {
      const int d = w * 32 + nf * 16 + i;
      short8 bv = *reinterpret_cast<const short8*>(&Vs[d * 40 + g * 8]);
      pv[pf][nf] = __builtin_amdgcn_mfma_f32_16x16x32_bf16(pa, bv, pv[pf][nf], 0, 0, 0);
    }
  }
  __builtin_amdgcn_s_setprio(0);

  // effect = pv + bo : row s = s0 + pf*16 + g*4 + j, col d = w*32 + nf*16 + i
  const int b_ = bh >> 2, h_ = bh & 3;
#pragma unroll
  for (int pf = 0; pf < 4; ++pf)
#pragma unroll
    for (int j = 0; j < 4; ++j) {
      const int row = s0 + pf * 16 + g * 4 + j;
      const float bias = bo[row];
#pragma unroll
      for (int nf = 0; nf < 2; ++nf)
        __builtin_nontemporal_store(
            pv[pf][nf][j] + bias,
            &effect[(size_t)(b_ * Sn + row) * En + h_ * Dn + w * 32 + nf * 16 + i]);
    }
}

// ---------------------------------------------------------------------------
extern "C" void kernel_launch(void* const* d_in, const int* in_sizes, int n_in,
                              void* d_out, int out_size, void* d_ws, size_t ws_size,
                              hipStream_t stream) {
  const float* x    = (const float*)d_in[0];
  const float* Wq   = (const float*)d_in[1];
  const float* Wk   = (const float*)d_in[2];
  const float* Wv   = (const float*)d_in[3];
  const float* Wepi = (const float*)d_in[4];
  const float* bq   = (const float*)d_in[5];
  const float* bk   = (const float*)d_in[6];
  const float* bv   = (const float*)d_in[7];
  const float* bo   = (const float*)d_in[8];

  float* effect = (float*)d_out;
  float* attn = effect + (size_t)Bn * Sn * En;              // attn region of d_out
  unsigned short* qkv = (unsigned short*)d_ws;              // q|k|v bf16 (50.3 MB)
  unsigned short* vT = qkv + (size_t)3 * BHn * Sn * Dn;     // v^T bf16 (16.8 MB)

  qkv_kernel<<<dim3(Mqkv / 128, En / 128, 3), 256, 0, stream>>>(x, Wq, Wk, Wv, bq, bk, bv, qkv);
  vtrans_kernel<<<dim3(Sn / 64, Dn / 64, BHn), 256, 0, stream>>>(
      qkv + (size_t)2 * BHn * Sn * Dn, vT);
  fused_attn8_kernel<<<dim3(1024), 256, 0, stream>>>(qkv, vT, Wepi, bo, attn, effect);
}